// Round 10
// baseline (1936.854 us; speedup 1.0000x reference)
//
#include <hip/hip_runtime.h>
#include <math.h>

typedef unsigned short u16;
typedef __attribute__((ext_vector_type(8))) short bf16x8;
typedef __attribute__((ext_vector_type(4))) float f32x4;
typedef __attribute__((ext_vector_type(4))) unsigned short u16x4;

#define NLAYERS 5
#define BATCH 8
#define SEQ 2048
#define CH 512
#define ROWS_TOTAL (BATCH * SEQ)   // 16384
#define HALF (SEQ / 2)             // 1024
#define ATTN_SCALE 0.04419417382415922f  // 512^-0.5

// LDS: staging As (128x64 u16 = 16 KB) + Bs (256x64 u16 = 32 KB) = 48 KB,
// aliased with the epilogue transpose buffer (32 x 132 fp32 = 16.9 KB).
#define SMEM_U16 24576

__device__ __forceinline__ u16 f2bf(float f) {
    unsigned u = __float_as_uint(f);
    u += 0x7fffu + ((u >> 16) & 1u);   // RNE
    return (u16)(u >> 16);
}

__device__ __forceinline__ u16x4 pack4(f32x4 v) {
    u16x4 o;
    o.x = f2bf(v[0]); o.y = f2bf(v[1]); o.z = f2bf(v[2]); o.w = f2bf(v[3]);
    return o;
}

__device__ __forceinline__ void nt_store(u16* p, u16x4 v) {
    __builtin_nontemporal_store(v, (u16x4*)p);
}
__device__ __forceinline__ void nt_storef(float* p, f32x4 v) {
    __builtin_nontemporal_store(v, (f32x4*)p);
}

// 16-byte async global->LDS DMA. LDS dest = wave-uniform base + lane*16.
__device__ __forceinline__ void llds16(const u16* g, u16* l) {
    __builtin_amdgcn_global_load_lds(
        (const __attribute__((address_space(1))) unsigned int*)g,
        (__attribute__((address_space(3))) unsigned int*)l, 16, 0, 0);
}

// XCD-aware decode for M=16384 row-panel GEMMs (qkv/fc1/fc2): XCD k
// (bid&7) owns row-tiles [16k,16k+16) for all col-tiles -> per-XCD L2
// working set = A-panel 2.1 MB + W <= 1.6 MB < 4 MB. (Round-9: fc1 improved
// 84 -> <70 us with this mapping.)
__device__ __forceinline__ void xcd_rc(int& rt, int& ct) {
    const int n = blockIdx.x;
    const int m = n >> 3;
    rt = (n & 7) * 16 + (m & 15);
    ct = m >> 4;
}

// ---------------------------------------------------------------------------
// WIDE bf16 MFMA GEMM tile: 128x256 C-tile, 256 threads (4 waves: wm=
// (wave&1)*64, wn=(wave>>1)*128), 16x16x32 MFMA, BK=64. Per k-iter: 64 MFMAs
// vs 12 DMA issues and 2 barriers — 2x the barrier amortization of the old
// 128x128 tile (round-9 qk: MfmaUtil 11.5% => barrier-drain-bound at K=512).
// A[m][k] row-major (lda), Bt[n][k] row-major (ldb; 256 rows staged).
// LDS unpadded [rows][64] u16; chunk position p holds global chunk p^(row&7)
// (measured 0 bank conflicts, rounds 3-9). Frag layout (verified):
// A [m=lane&15][k=quad*8+j]; C/D col=lane&15, row=quad*4+reg.
// ---------------------------------------------------------------------------
__device__ __forceinline__ void mm_core_w(
    const u16* __restrict__ A, int lda,
    const u16* __restrict__ Bt, int ldb,
    int row0, int col0, int K,
    u16* As, u16* Bs, f32x4 acc[4][8])
{
    const int tid  = threadIdx.x;
    const int wave = tid >> 6, lane = tid & 63;
    const int wm = (wave & 1) * 64, wn = (wave >> 1) * 128;
    const int q  = lane >> 4,  ln = lane & 15;

    const int sr8 = lane >> 3;               // row within 8-row group
    const int sc  = (lane & 7) ^ sr8;        // swizzled global chunk to fetch
    const u16* gA = A  + (size_t)(row0 + wave * 8 + sr8) * lda + sc * 8;
    const u16* gB = Bt + (size_t)(col0 + wave * 8 + sr8) * ldb + sc * 8;
    u16* lA = As + wave * 512;               // (wave*8 rows) * 64 elems
    u16* lB = Bs + wave * 512;

    int aoff[2][4], boff[2][8];
#pragma unroll
    for (int h = 0; h < 2; ++h) {
        const int pos = (((h * 4 + q) ^ (ln & 7)) * 8);
#pragma unroll
        for (int t = 0; t < 4; ++t)
            aoff[h][t] = (wm + t * 16 + ln) * 64 + pos;
#pragma unroll
        for (int t = 0; t < 8; ++t)
            boff[h][t] = (wn + t * 16 + ln) * 64 + pos;
    }

#pragma unroll
    for (int ti = 0; ti < 4; ++ti)
#pragma unroll
        for (int tj = 0; tj < 8; ++tj)
#pragma unroll
            for (int e = 0; e < 4; ++e) acc[ti][tj][e] = 0.f;

    for (int k0 = 0; k0 < K; k0 += 64) {
        __syncthreads();               // prev iter's frag reads drained
#pragma unroll
        for (int i = 0; i < 4; ++i)    // A: 128 rows
            llds16(gA + (size_t)i * 32 * lda, lA + i * 2048);
#pragma unroll
        for (int i = 0; i < 8; ++i)    // B: 256 rows
            llds16(gB + (size_t)i * 32 * ldb, lB + i * 2048);
        gA += 64; gB += 64;
        __syncthreads();               // DMA drained -> LDS visible
#pragma unroll
        for (int h = 0; h < 2; ++h) {
            bf16x8 af[4], bfv[8];
#pragma unroll
            for (int t = 0; t < 4; ++t) af[t]  = *(const bf16x8*)&As[aoff[h][t]];
#pragma unroll
            for (int t = 0; t < 8; ++t) bfv[t] = *(const bf16x8*)&Bs[boff[h][t]];
#pragma unroll
            for (int ti = 0; ti < 4; ++ti)
#pragma unroll
                for (int tj = 0; tj < 8; ++tj)
                    acc[ti][tj] = __builtin_amdgcn_mfma_f32_16x16x32_bf16(
                        af[ti], bfv[tj], acc[ti][tj], 0, 0, 0);
        }
    }
}

// ---------------------------------------------------------------------------
// Wide epilogue transpose: 8 passes of 32 rows x 128 cols through LDS
// (eb = 32x132 fp32, aliases staging). Column half h is owned entirely by
// waves with (wave>>1)==h; pass p2 selects the row quarter. emit(row 0..127,
// col 0..255 multiple of 4, f32x4).
// ---------------------------------------------------------------------------
template <typename F>
__device__ __forceinline__ void epi_emit_w(f32x4 acc[4][8], float* eb, F emit)
{
    const int tid = threadIdx.x, wave = tid >> 6, lane = tid & 63;
    const int q = lane >> 4, ln = lane & 15;
    const int wh = wave >> 1, wp = wave & 1;
#pragma unroll
    for (int h = 0; h < 2; ++h) {
#pragma unroll
        for (int p2 = 0; p2 < 4; ++p2) {
            __syncthreads();   // frag reads / previous pass reads done
            if (wh == h && wp == (p2 >> 1)) {
                const int tibase = (p2 & 1) * 2;
#pragma unroll
                for (int tj = 0; tj < 8; ++tj)
#pragma unroll
                    for (int t2 = 0; t2 < 2; ++t2)
#pragma unroll
                        for (int r = 0; r < 4; ++r)
                            eb[(t2 * 16 + q * 4 + r) * 132 + tj * 16 + ln] =
                                acc[tibase + t2][tj][r];
            }
            __syncthreads();
#pragma unroll
            for (int s = 0; s < 4; ++s) {
                const int row = s * 8 + (tid >> 5);        // 0..31
                const int col = (tid & 31) * 4;            // 0..124
                f32x4 v = *(const f32x4*)&eb[row * 132 + col];
                emit(p2 * 32 + row, h * 128 + col, v);
            }
        }
    }
}

// ---------------------------------------------------------------------------
// QKV GEMM: A=xb[16384][512], Bt=qkv_wt[1536][512]. 1-D grid 768, row-panel
// XCD swizzle, 256-col tiles: ct 0-1 = Q (pre-scaled), 2-3 = K, 4-5 = V
// (direct transposed store Vt[b][c][j]).
// ---------------------------------------------------------------------------
__global__ __launch_bounds__(256) void qkv_gemm(
    const u16* __restrict__ A, const u16* __restrict__ Bt,
    const float* __restrict__ bias,
    u16* __restrict__ Qb, u16* __restrict__ Kb, u16* __restrict__ Vt)
{
    __shared__ __align__(16) u16 SMEM[SMEM_U16];
    u16* As = SMEM; u16* Bs = SMEM + 8192;
    f32x4 acc[4][8];
    int rt, ct; xcd_rc(rt, ct);
    const int row0 = rt * 128, col0 = ct * 256;
    mm_core_w(A, CH, Bt, CH, row0, col0, CH, As, Bs, acc);

    if (ct < 4) {   // Q or K region (block-uniform)
        u16* dst = (ct < 2) ? Qb : Kb;
        const int cbase = (ct < 2) ? col0 : col0 - CH;
        const float sc = (ct < 2) ? ATTN_SCALE : 1.0f;
        epi_emit_w(acc, (float*)SMEM, [&](int row, int col, f32x4 v) {
            const float4 bb = *(const float4*)&bias[col0 + col];
            v[0] = (v[0] + bb.x) * sc; v[1] = (v[1] + bb.y) * sc;
            v[2] = (v[2] + bb.z) * sc; v[3] = (v[3] + bb.w) * sc;
            nt_store(&dst[(size_t)(row0 + row) * CH + cbase + col], pack4(v));
        });
    } else {        // V region: direct path, transposed store
        const int tid = threadIdx.x, wave = tid >> 6, lane = tid & 63;
        const int wm = (wave & 1) * 64, wn = (wave >> 1) * 128;
        const int q = lane >> 4, ln = lane & 15;
#pragma unroll
        for (int tj = 0; tj < 8; ++tj) {
            const int gcol = col0 + wn + tj * 16 + ln;
            const float bv = bias[gcol];
#pragma unroll
            for (int ti = 0; ti < 4; ++ti) {
                const int grow = row0 + wm + ti * 16 + q * 4;
                const int b = grow >> 11, j = grow & (SEQ - 1);
                u16x4 o;
                o.x = f2bf(acc[ti][tj][0] + bv);
                o.y = f2bf(acc[ti][tj][1] + bv);
                o.z = f2bf(acc[ti][tj][2] + bv);
                o.w = f2bf(acc[ti][tj][3] + bv);
                nt_store(&Vt[(size_t)b * CH * SEQ +
                             (size_t)(gcol - 2 * CH) * SEQ + j], o);
            }
        }
    }
}

// ---------------------------------------------------------------------------
// QK^T GEMM, fused unnormalized softmax. 1-D grid 1024: b=id&7 (XCD=batch:
// per-XCD working set = K 2MB + Q-tile, L2-resident), px=(id>>3)&7 covers
// j-tiles {2px, 2px+1}, it=id>>6. Fully-masked j-tiles are computed but not
// stored (pv never reads past tile it). Writes P'=exp(s) bf16, accumulates
// rowsum. Max-free exp safe (score std ~0.2; fminf(60) guard).
// ---------------------------------------------------------------------------
__global__ __launch_bounds__(256) void qk_gemm(
    const u16* __restrict__ Qb, const u16* __restrict__ Kb,
    u16* __restrict__ Sb, float* __restrict__ rowsum)
{
    const int id = blockIdx.x;
    const int b = id & 7, px = (id >> 3) & 7, it = id >> 6;
    if (it < 8) { if (px >= 4) return; } else if (2 * px > it) return;
    __shared__ __align__(16) u16 SMEM[SMEM_U16];
    u16* As = SMEM; u16* Bs = SMEM + 8192;
    f32x4 acc[4][8];
    const u16* A  = Qb + (size_t)b * SEQ * CH;
    const u16* Bt = Kb + (size_t)b * SEQ * CH;
    u16* S = Sb + (size_t)b * SEQ * SEQ;
    const int row0 = it * 128, col0 = px * 256;
    mm_core_w(A, CH, Bt, CH, row0, col0, CH, As, Bs, acc);

    const bool upper = (it < 8);
    const int tid = threadIdx.x;
    epi_emit_w(acc, (float*)SMEM, [&](int row, int col, f32x4 v) {
        const int grow = row0 + row;        // i within batch
        const int gcol = col0 + col;        // j
        f32x4 pv;
#pragma unroll
        for (int e = 0; e < 4; ++e) {
            const bool allowed = upper || (gcol + e <= grow);
            pv[e] = allowed ? __expf(fminf(v[e], 60.f)) : 0.f;
        }
        if (upper || (gcol >> 7) <= it)
            nt_store(&S[(size_t)grow * SEQ + gcol], pack4(pv));
        float rs = pv[0] + pv[1] + pv[2] + pv[3];
        rs += __shfl_xor(rs, 1, 64);
        rs += __shfl_xor(rs, 2, 64);
        rs += __shfl_xor(rs, 4, 64);
        rs += __shfl_xor(rs, 8, 64);
        rs += __shfl_xor(rs, 16, 64);
        if ((tid & 31) == 0)
            atomicAdd(&rowsum[b * SEQ + grow], rs);
    });
}

// ---------------------------------------------------------------------------
// PV GEMM, full-K per block, normalized output, nt-stores. 1-D grid 256:
// b=id&7 (XCD=batch: Vt 2MB L2-resident), ct=(id>>3)&1 (256 cols), heavy
// row-tiles first. O[b][i][c] = (P'[b][i][:Kfull] @ V) / rowsum_i.
// ---------------------------------------------------------------------------
__global__ __launch_bounds__(256) void pv_gemm(
    const u16* __restrict__ Sb, const u16* __restrict__ Vt,
    const float* __restrict__ rowsum, float* __restrict__ O)
{
    const int id = blockIdx.x;
    const int b = id & 7, ct = (id >> 3) & 1, it = 15 - (id >> 4);
    const int Kfull = ((it < 8) ? 8 : (it + 1)) * 128;
    __shared__ __align__(16) u16 SMEM[SMEM_U16];
    u16* As = SMEM; u16* Bs = SMEM + 8192;
    f32x4 acc[4][8];
    const u16* A  = Sb + (size_t)b * SEQ * SEQ;
    const u16* Bt = Vt + (size_t)b * CH * SEQ;
    const int row0 = it * 128, col0 = ct * 256;
    mm_core_w(A, SEQ, Bt, SEQ, row0, col0, Kfull, As, Bs, acc);

    epi_emit_w(acc, (float*)SMEM, [&](int row, int col, f32x4 v) {
        const int grow = row0 + row;
        const float rden = 1.0f / rowsum[b * SEQ + grow];
        v[0] *= rden; v[1] *= rden; v[2] *= rden; v[3] *= rden;
        nt_storef(&O[(size_t)(b * SEQ + grow) * CH + col0 + col], v);
    });
}

// ---------------------------------------------------------------------------
// fc1: bf16 in/out, exact GELU epilogue. 1-D grid 512, row-panel XCD swizzle.
// ---------------------------------------------------------------------------
__global__ __launch_bounds__(256) void fc1_gemm(
    const u16* __restrict__ A, const u16* __restrict__ Bt,
    const float* __restrict__ bias, u16* __restrict__ H)
{
    __shared__ __align__(16) u16 SMEM[SMEM_U16];
    u16* As = SMEM; u16* Bs = SMEM + 8192;
    f32x4 acc[4][8];
    int rt, ct; xcd_rc(rt, ct);
    const int row0 = rt * 128, col0 = ct * 256;
    mm_core_w(A, CH, Bt, CH, row0, col0, CH, As, Bs, acc);
    epi_emit_w(acc, (float*)SMEM, [&](int row, int col, f32x4 v) {
        const float4 bb = *(const float4*)&bias[col0 + col];
        v[0] += bb.x; v[1] += bb.y; v[2] += bb.z; v[3] += bb.w;
#pragma unroll
        for (int e = 0; e < 4; ++e)
            v[e] = 0.5f * v[e] * (1.f + erff(v[e] * 0.70710678118654752f));
        nt_store(&H[(size_t)(row0 + row) * (2 * CH) + col0 + col], pack4(v));
    });
}

// ---------------------------------------------------------------------------
// fc2: bf16 in, +bias + fp32 residual (normalized O). Writes bf16 Xb always;
// fp32 X only on the final layer. 1-D grid 256, row-panel XCD swizzle.
// ---------------------------------------------------------------------------
template <bool WRITE_X>
__global__ __launch_bounds__(256) void fc2_gemm(
    const u16* __restrict__ A, const u16* __restrict__ Bt,
    const float* __restrict__ bias, float* __restrict__ X,
    u16* __restrict__ Xb)
{
    __shared__ __align__(16) u16 SMEM[SMEM_U16];
    u16* As = SMEM; u16* Bs = SMEM + 8192;
    f32x4 acc[4][8];
    int rt, ct; xcd_rc(rt, ct);
    const int row0 = rt * 128, col0 = ct * 256;
    mm_core_w(A, 2 * CH, Bt, 2 * CH, row0, col0, 2 * CH, As, Bs, acc);
    epi_emit_w(acc, (float*)SMEM, [&](int row, int col, f32x4 v) {
        const size_t idx = (size_t)(row0 + row) * CH + col0 + col;
        const float4 bb = *(const float4*)&bias[col0 + col];
        const f32x4 xv = *(const f32x4*)&X[idx];
        v[0] += bb.x + xv[0]; v[1] += bb.y + xv[1];
        v[2] += bb.z + xv[2]; v[3] += bb.w + xv[3];
        if (WRITE_X) nt_storef(&X[idx], v);
        nt_store(&Xb[idx], pack4(v));
    });
}

// ---------------------------------------------------------------------------
// LayerNorm: fp32 in (normalized attention out), bf16 out (feeds fc1).
// ---------------------------------------------------------------------------
__device__ __forceinline__ float block_sum(float v, volatile float* red, int tid)
{
#pragma unroll
    for (int off = 1; off < 64; off <<= 1) v += __shfl_xor(v, off, 64);
    __syncthreads();
    if ((tid & 63) == 0) red[tid >> 6] = v;
    __syncthreads();
    return red[0] + red[1] + red[2] + red[3];
}

__global__ __launch_bounds__(256) void ln_kernel(
    const float* __restrict__ x, const float* __restrict__ g,
    const float* __restrict__ bta, u16* __restrict__ y)
{
    __shared__ float red[4];
    const int tid = threadIdx.x;
    const size_t base = (size_t)blockIdx.x * CH;
    float x0 = x[base + tid];
    float x1 = x[base + 256 + tid];
    float mu = block_sum(x0 + x1, red, tid) * (1.f / CH);
    float d0 = x0 - mu, d1 = x1 - mu;
    float var = block_sum(d0 * d0 + d1 * d1, red, tid) * (1.f / CH);
    float w = 1.f / sqrtf(var + 1e-5f);
    y[base + tid]       = f2bf(d0 * w * g[tid]       + bta[tid]);
    y[base + 256 + tid] = f2bf(d1 * w * g[256 + tid] + bta[256 + tid]);
}

// ---------------------------------------------------------------------------
// fp32 -> bf16 elementwise (4/thread).
// ---------------------------------------------------------------------------
__global__ __launch_bounds__(256) void f2bf_kernel(
    const float* __restrict__ in, u16* __restrict__ out)
{
    const int i = blockIdx.x * 256 + threadIdx.x;
    float4 v = ((const float4*)in)[i];
    ushort4 o;
    o.x = f2bf(v.x); o.y = f2bf(v.y); o.z = f2bf(v.z); o.w = f2bf(v.w);
    ((ushort4*)out)[i] = o;
}

// ---------------------------------------------------------------------------
// Weight transpose-convert: in fp32 [L][K][N] -> out bf16 [L][N][K].
// ---------------------------------------------------------------------------
__global__ __launch_bounds__(256) void wtrans_kernel(
    const float* __restrict__ in, u16* __restrict__ out, int K, int N)
{
    __shared__ float tile[32][33];
    const int l = blockIdx.z;
    in  += (size_t)l * K * N;
    out += (size_t)l * K * N;
    const int n0 = blockIdx.x * 32, k0 = blockIdx.y * 32;
    const int r = threadIdx.x >> 3, c4 = (threadIdx.x & 7) * 4;
    float4 v = *(const float4*)&in[(size_t)(k0 + r) * N + n0 + c4];
    tile[r][c4 + 0] = v.x; tile[r][c4 + 1] = v.y;
    tile[r][c4 + 2] = v.z; tile[r][c4 + 3] = v.w;
    __syncthreads();
    ushort4 o;
    o.x = f2bf(tile[c4 + 0][r]); o.y = f2bf(tile[c4 + 1][r]);
    o.z = f2bf(tile[c4 + 2][r]); o.w = f2bf(tile[c4 + 3][r]);
    *(ushort4*)&out[(size_t)(n0 + r) * K + k0 + c4] = o;
}

// ---------------------------------------------------------------------------
extern "C" void kernel_launch(void* const* d_in, const int* in_sizes, int n_in,
                              void* d_out, int out_size, void* d_ws, size_t ws_size,
                              hipStream_t stream)
{
    const float* x_in  = (const float*)d_in[0];
    const float* qkv_w = (const float*)d_in[1];
    const float* qkv_b = (const float*)d_in[2];
    const float* ln_g  = (const float*)d_in[3];
    const float* ln_b  = (const float*)d_in[4];
    const float* fc1_w = (const float*)d_in[5];
    const float* fc1_b = (const float*)d_in[6];
    const float* fc2_w = (const float*)d_in[7];
    const float* fc2_b = (const float*)d_in[8];

    float* xbuf = (float*)d_out;   // fp32 working x (B,N,C) — also final out

    // Workspace carve (bytes). Total ≈ 152.7 MB.
    char* p = (char*)d_ws;
    u16* qkv_wt = (u16*)p; p += (size_t)NLAYERS * 1536 * 512 * 2;
    u16* fc1_wt = (u16*)p; p += (size_t)NLAYERS * 1024 * 512 * 2;
    u16* fc2_wt = (u16*)p; p += (size_t)NLAYERS * 512 * 1024 * 2;
    u16* xb = (u16*)p; p += (size_t)ROWS_TOTAL * CH * 2;
    u16* Qb = (u16*)p; p += (size_t)ROWS_TOTAL * CH * 2;
    u16* Kb = (u16*)p; p += (size_t)ROWS_TOTAL * CH * 2;
    u16* Vt = (u16*)p; p += (size_t)ROWS_TOTAL * CH * 2;
    float* rowsum = (float*)p; p += (size_t)ROWS_TOTAL * 4;
    u16* Sb = (u16*)p;                       // attention phase
    u16* yb = Sb;                            // alias: LN out (MLP phase)
    u16* hb = Sb + (size_t)ROWS_TOTAL * CH;  // alias: GELU out (MLP phase)

    const dim3 blk(256);

    f2bf_kernel<<<dim3(ROWS_TOTAL * CH / 1024), blk, 0, stream>>>(x_in, xb);
    wtrans_kernel<<<dim3(1536 / 32, 512 / 32, NLAYERS), blk, 0, stream>>>(
        qkv_w, qkv_wt, 512, 1536);
    wtrans_kernel<<<dim3(1024 / 32, 512 / 32, NLAYERS), blk, 0, stream>>>(
        fc1_w, fc1_wt, 512, 1024);
    wtrans_kernel<<<dim3(512 / 32, 1024 / 32, NLAYERS), blk, 0, stream>>>(
        fc2_w, fc2_wt, 1024, 512);

    for (int l = 0; l < NLAYERS; ++l) {
        qkv_gemm<<<dim3(128 * 6), blk, 0, stream>>>(
            xb, qkv_wt + (size_t)l * 1536 * 512, qkv_b + (size_t)l * 1536,
            Qb, Kb, Vt);
        hipMemsetAsync(rowsum, 0, (size_t)ROWS_TOTAL * 4, stream);
        qk_gemm<<<dim3(8 * 8 * 16), blk, 0, stream>>>(Qb, Kb, Sb, rowsum);
        pv_gemm<<<dim3(8 * 2 * 16), blk, 0, stream>>>(Sb, Vt, rowsum, xbuf);
        ln_kernel<<<dim3(ROWS_TOTAL), blk, 0, stream>>>(
            xbuf, ln_g + (size_t)l * CH, ln_b + (size_t)l * CH, yb);
        fc1_gemm<<<dim3(128 * 4), blk, 0, stream>>>(
            yb, fc1_wt + (size_t)l * 1024 * 512, fc1_b + (size_t)l * 1024, hb);
        if (l < NLAYERS - 1)
            fc2_gemm<false><<<dim3(128 * 2), blk, 0, stream>>>(
                hb, fc2_wt + (size_t)l * 512 * 1024, fc2_b + (size_t)l * 512,
                xbuf, xb);
        else
            fc2_gemm<true><<<dim3(128 * 2), blk, 0, stream>>>(
                hb, fc2_wt + (size_t)l * 512 * 1024, fc2_b + (size_t)l * 512,
                xbuf, xb);
    }
}

// Round 11
// 1147.340 us; speedup vs baseline: 1.6881x; 1.6881x over previous
//
#include <hip/hip_runtime.h>
#include <math.h>

typedef unsigned short u16;
typedef __attribute__((ext_vector_type(8))) short bf16x8;
typedef __attribute__((ext_vector_type(4))) float f32x4;
typedef __attribute__((ext_vector_type(4))) unsigned short u16x4;

#define NLAYERS 5
#define BATCH 8
#define SEQ 2048
#define CH 512
#define ROWS_TOTAL (BATCH * SEQ)   // 16384
#define HALF (SEQ / 2)             // 1024
#define ATTN_SCALE 0.04419417382415922f  // 512^-0.5

// Shared memory: mm_core staging (As 16KB + Bs 16KB = 32768 B) aliased with
// the epilogue transpose buffer (32 x 132 fp32 = 16896 B). Block LDS =
// 32768 B -> 5 blocks/CU. (Round-10's 128x256 tile needed 48 KB + 276 regs
// -> 1 wave/SIMD occupancy cliff, MfmaUtil 8.6% — reverted.)
#define SMEM_U16 16384

__device__ __forceinline__ u16 f2bf(float f) {
    unsigned u = __float_as_uint(f);
    u += 0x7fffu + ((u >> 16) & 1u);   // RNE
    return (u16)(u >> 16);
}

__device__ __forceinline__ u16x4 pack4(f32x4 v) {
    u16x4 o;
    o.x = f2bf(v[0]); o.y = f2bf(v[1]); o.z = f2bf(v[2]); o.w = f2bf(v[3]);
    return o;
}

// Plain 16B stores (nt-stores measured no FETCH change in round 9, and
// streaming hints work against the L2-locality mappings below).
__device__ __forceinline__ void st16(u16* p, u16x4 v) { *(u16x4*)p = v; }
__device__ __forceinline__ void st16f(float* p, f32x4 v) { *(f32x4*)p = v; }

// 16-byte async global->LDS DMA. LDS dest = wave-uniform base + lane*16.
__device__ __forceinline__ void llds16(const u16* g, u16* l) {
    __builtin_amdgcn_global_load_lds(
        (const __attribute__((address_space(1))) unsigned int*)g,
        (__attribute__((address_space(3))) unsigned int*)l, 16, 0, 0);
}

// XCD-aware decode for M=16384 row-panel GEMMs (qkv/fc1/fc2): XCD k
// (bid&7) owns row-tiles [16k,16k+16) for all col-tiles -> per-XCD L2
// working set = A-panel 2.1 MB + W <= 1.6 MB < 4 MB. (fc1 improved
// measurably with this in round 9.)
__device__ __forceinline__ void xcd_rc(int& rt, int& ct) {
    const int n = blockIdx.x;
    const int m = n >> 3;
    rt = (n & 7) * 16 + (m & 15);
    ct = m >> 4;
}

// ---------------------------------------------------------------------------
// Core bf16 MFMA GEMM tile: 128x128 C-tile, 256 threads (4 waves, 2x2 of
// 64x64), 16x16x32 MFMA, BK=64 (32 MFMAs per barrier pair). A[m][k]
// row-major (lda), Bt[n][k] row-major (ldb). LDS unpadded [128][64] u16 per
// matrix; chunk position p holds global chunk p^(row&7) (measured 0 bank
// conflicts, rounds 3-10). Frag layout (verified): A [m=lane&15][k=quad*8+j];
// C/D col=lane&15, row=quad*4+reg. VGPR ~84 -> healthy occupancy.
// ---------------------------------------------------------------------------
__device__ __forceinline__ void mm_core(
    const u16* __restrict__ A, int lda,
    const u16* __restrict__ Bt, int ldb,
    int row0, int col0, int K,
    u16* As, u16* Bs, f32x4 acc[4][4])
{
    const int tid  = threadIdx.x;
    const int wave = tid >> 6, lane = tid & 63;
    const int wm = (wave & 1) * 64, wn = (wave >> 1) * 64;
    const int q  = lane >> 4,  ln = lane & 15;

    const int sr8 = lane >> 3;               // row within 8-row group
    const int sc  = (lane & 7) ^ sr8;        // swizzled global chunk to fetch
    const u16* gA = A  + (size_t)(row0 + wave * 8 + sr8) * lda + sc * 8;
    const u16* gB = Bt + (size_t)(col0 + wave * 8 + sr8) * ldb + sc * 8;
    u16* lA = As + wave * 512;               // (wave*8 rows) * 64 elems
    u16* lB = Bs + wave * 512;

    int aoff[2][4], boff[2][4];
#pragma unroll
    for (int h = 0; h < 2; ++h) {
        const int pos = (((h * 4 + q) ^ (ln & 7)) * 8);
#pragma unroll
        for (int t = 0; t < 4; ++t) {
            aoff[h][t] = (wm + t * 16 + ln) * 64 + pos;
            boff[h][t] = (wn + t * 16 + ln) * 64 + pos;
        }
    }

#pragma unroll
    for (int ti = 0; ti < 4; ++ti)
#pragma unroll
        for (int tj = 0; tj < 4; ++tj)
#pragma unroll
            for (int e = 0; e < 4; ++e) acc[ti][tj][e] = 0.f;

    for (int k0 = 0; k0 < K; k0 += 64) {
        __syncthreads();               // prev iter's frag reads drained
#pragma unroll
        for (int i = 0; i < 4; ++i)    // A: 4 issues x (4 waves x 8 rows)
            llds16(gA + (size_t)i * 32 * lda, lA + i * 2048);
#pragma unroll
        for (int i = 0; i < 4; ++i)
            llds16(gB + (size_t)i * 32 * ldb, lB + i * 2048);
        gA += 64; gB += 64;
        __syncthreads();               // DMA drained -> LDS visible
#pragma unroll
        for (int h = 0; h < 2; ++h) {
            bf16x8 af[4], bfv[4];
#pragma unroll
            for (int t = 0; t < 4; ++t) af[t]  = *(const bf16x8*)&As[aoff[h][t]];
#pragma unroll
            for (int t = 0; t < 4; ++t) bfv[t] = *(const bf16x8*)&Bs[boff[h][t]];
#pragma unroll
            for (int ti = 0; ti < 4; ++ti)
#pragma unroll
                for (int tj = 0; tj < 4; ++tj)
                    acc[ti][tj] = __builtin_amdgcn_mfma_f32_16x16x32_bf16(
                        af[ti], bfv[tj], acc[ti][tj], 0, 0, 0);
        }
    }
}

// ---------------------------------------------------------------------------
// Epilogue transpose: round-trip acc through LDS so each thread owns a
// contiguous float4 of one row -> vectorized global I/O. FOUR passes of 32
// rows (eb = 32 x 132 fp32 = 16.9 KB, aliases staging; keeps block LDS at
// 32 KB for 5 blocks/CU). emit(local_row 0..127, col multiple of 4, f32x4).
// ---------------------------------------------------------------------------
template <typename F>
__device__ __forceinline__ void epi_emit(f32x4 acc[4][4], float* eb, F emit)
{
    const int tid = threadIdx.x, wave = tid >> 6, lane = tid & 63;
    const int wn = (wave >> 1) * 64;
    const int q = lane >> 4, ln = lane & 15;
#pragma unroll
    for (int p = 0; p < 4; ++p) {
        __syncthreads();   // frag reads / pass-(p-1) epi reads done
        if ((wave & 1) == (p >> 1)) {
            const int tibase = (p & 1) * 2;
#pragma unroll
            for (int tj = 0; tj < 4; ++tj)
#pragma unroll
                for (int t2 = 0; t2 < 2; ++t2)
#pragma unroll
                    for (int r = 0; r < 4; ++r)
                        eb[(t2 * 16 + q * 4 + r) * 132 + wn + tj * 16 + ln] =
                            acc[tibase + t2][tj][r];
        }
        __syncthreads();
#pragma unroll
        for (int s = 0; s < 4; ++s) {
            const int row = s * 8 + (tid >> 5);        // 0..31
            const int col = (tid & 31) * 4;
            f32x4 v = *(const f32x4*)&eb[row * 132 + col];
            emit(p * 32 + row, col, v);
        }
    }
}

// ---------------------------------------------------------------------------
// QKV GEMM: A=xb[16384][512], Bt=qkv_wt[1536][512]. 1-D grid (128*12),
// row-panel XCD swizzle. Q (pre-scaled) and K use the vectorized epi; V
// region (ct>=8) keeps the direct acc path (transposed store Vt[b][c][j]).
// ---------------------------------------------------------------------------
__global__ __launch_bounds__(256) void qkv_gemm(
    const u16* __restrict__ A, const u16* __restrict__ Bt,
    const float* __restrict__ bias,
    u16* __restrict__ Qb, u16* __restrict__ Kb, u16* __restrict__ Vt)
{
    __shared__ __align__(16) u16 SMEM[SMEM_U16];
    u16* As = SMEM; u16* Bs = SMEM + 8192;
    f32x4 acc[4][4];
    int rt, ct; xcd_rc(rt, ct);
    const int row0 = rt * 128, col0 = ct * 128;
    mm_core(A, CH, Bt, CH, row0, col0, CH, As, Bs, acc);

    if (ct < 8) {   // Q or K region (block-uniform)
        u16* dst = (ct < 4) ? Qb : Kb;
        const int cbase = (ct < 4) ? col0 : col0 - CH;
        const float sc = (ct < 4) ? ATTN_SCALE : 1.0f;
        epi_emit(acc, (float*)SMEM, [&](int row, int col, f32x4 v) {
            const float4 bb = *(const float4*)&bias[col0 + col];
            v[0] = (v[0] + bb.x) * sc; v[1] = (v[1] + bb.y) * sc;
            v[2] = (v[2] + bb.z) * sc; v[3] = (v[3] + bb.w) * sc;
            st16(&dst[(size_t)(row0 + row) * CH + cbase + col], pack4(v));
        });
    } else {                // V region: direct path, transposed store
        const int tid = threadIdx.x, wave = tid >> 6, lane = tid & 63;
        const int wm = (wave & 1) * 64, wn = (wave >> 1) * 64;
        const int q = lane >> 4, ln = lane & 15;
#pragma unroll
        for (int tj = 0; tj < 4; ++tj) {
            const int gcol = col0 + wn + tj * 16 + ln;
            const float bv = bias[gcol];
#pragma unroll
            for (int ti = 0; ti < 4; ++ti) {
                const int grow = row0 + wm + ti * 16 + q * 4;
                const int b = grow >> 11, j = grow & (SEQ - 1);
                u16x4 o;
                o.x = f2bf(acc[ti][tj][0] + bv);
                o.y = f2bf(acc[ti][tj][1] + bv);
                o.z = f2bf(acc[ti][tj][2] + bv);
                o.w = f2bf(acc[ti][tj][3] + bv);
                st16(&Vt[(size_t)b * CH * SEQ +
                         (size_t)(gcol - 2 * CH) * SEQ + j], o);
            }
        }
    }
}

// ---------------------------------------------------------------------------
// QK^T GEMM, fused unnormalized softmax. 1-D grid 2048: b=id&7 -> XCD=batch
// (round-10 measured FETCH 74 -> 16.6 MB with this mapping: K 2MB resident
// in the owner XCD's L2). jt=(id>>3)&15, it=id>>7; masked tiles early-out.
// Writes P'=exp(s) bf16 (0 where masked), accumulates rowsum. Max-free exp
// safe (score std ~0.2; fminf(60) guard); normalization applied in pv.
// ---------------------------------------------------------------------------
__global__ __launch_bounds__(256) void qk_gemm(
    const u16* __restrict__ Qb, const u16* __restrict__ Kb,
    u16* __restrict__ Sb, float* __restrict__ rowsum)
{
    const int id = blockIdx.x;
    const int b = id & 7, jt = (id >> 3) & 15, it = id >> 7;
    if (it < 8) { if (jt >= 8) return; } else if (jt > it) return;
    __shared__ __align__(16) u16 SMEM[SMEM_U16];
    u16* As = SMEM; u16* Bs = SMEM + 8192;
    f32x4 acc[4][4];
    const u16* A  = Qb + (size_t)b * SEQ * CH;
    const u16* Bt = Kb + (size_t)b * SEQ * CH;
    u16* S = Sb + (size_t)b * SEQ * SEQ;
    const int row0 = it * 128, col0 = jt * 128;
    mm_core(A, CH, Bt, CH, row0, col0, CH, As, Bs, acc);

    const bool upper = (it < 8);
    const int tid = threadIdx.x;
    epi_emit(acc, (float*)SMEM, [&](int row, int col, f32x4 v) {
        const int grow = row0 + row;        // i within batch
        const int gcol = col0 + col;        // j
        f32x4 pv;
#pragma unroll
        for (int e = 0; e < 4; ++e) {
            const bool allowed = upper || (gcol + e <= grow);
            pv[e] = allowed ? __expf(fminf(v[e], 60.f)) : 0.f;
        }
        st16(&S[(size_t)grow * SEQ + gcol], pack4(pv));
        float rs = pv[0] + pv[1] + pv[2] + pv[3];
        rs += __shfl_xor(rs, 1, 64);
        rs += __shfl_xor(rs, 2, 64);
        rs += __shfl_xor(rs, 4, 64);
        rs += __shfl_xor(rs, 8, 64);
        rs += __shfl_xor(rs, 16, 64);
        if ((tid & 31) == 0)
            atomicAdd(&rowsum[b * SEQ + grow], rs);
    });
}

// ---------------------------------------------------------------------------
// PV GEMM, full-K per block, normalized output. 1-D grid 512: b=id&7 ->
// XCD=batch (Vt 2MB L2-resident), ct=(id>>3)&3, heavy row-tiles first.
// O[b][i][c] = (P'[b][i][:Kfull] @ V) / rowsum_i.
// ---------------------------------------------------------------------------
__global__ __launch_bounds__(256) void pv_gemm(
    const u16* __restrict__ Sb, const u16* __restrict__ Vt,
    const float* __restrict__ rowsum, float* __restrict__ O)
{
    const int n = blockIdx.x;
    const int b = n & 7, m = n >> 3;        // m = 0..63
    const int it = 15 - (m >> 2), ct = m & 3;
    const int Kfull = ((it < 8) ? 8 : (it + 1)) * 128;
    __shared__ __align__(16) u16 SMEM[SMEM_U16];
    u16* As = SMEM; u16* Bs = SMEM + 8192;
    f32x4 acc[4][4];
    const u16* A  = Sb + (size_t)b * SEQ * SEQ;
    const u16* Bt = Vt + (size_t)b * CH * SEQ;
    const int row0 = it * 128, col0 = ct * 128;
    mm_core(A, SEQ, Bt, SEQ, row0, col0, Kfull, As, Bs, acc);

    epi_emit(acc, (float*)SMEM, [&](int row, int col, f32x4 v) {
        const int grow = row0 + row;
        const float rden = 1.0f / rowsum[b * SEQ + grow];
        v[0] *= rden; v[1] *= rden; v[2] *= rden; v[3] *= rden;
        st16f(&O[(size_t)(b * SEQ + grow) * CH + col0 + col], v);
    });
}

// ---------------------------------------------------------------------------
// fc1: bf16 in/out, exact GELU epilogue. Row-panel XCD swizzle.
// ---------------------------------------------------------------------------
__global__ __launch_bounds__(256) void fc1_gemm(
    const u16* __restrict__ A, const u16* __restrict__ Bt,
    const float* __restrict__ bias, u16* __restrict__ H)
{
    __shared__ __align__(16) u16 SMEM[SMEM_U16];
    u16* As = SMEM; u16* Bs = SMEM + 8192;
    f32x4 acc[4][4];
    int rt, ct; xcd_rc(rt, ct);
    const int row0 = rt * 128, col0 = ct * 128;
    mm_core(A, CH, Bt, CH, row0, col0, CH, As, Bs, acc);
    epi_emit(acc, (float*)SMEM, [&](int row, int col, f32x4 v) {
        const float4 bb = *(const float4*)&bias[col0 + col];
        v[0] += bb.x; v[1] += bb.y; v[2] += bb.z; v[3] += bb.w;
#pragma unroll
        for (int e = 0; e < 4; ++e)
            v[e] = 0.5f * v[e] * (1.f + erff(v[e] * 0.70710678118654752f));
        st16(&H[(size_t)(row0 + row) * (2 * CH) + col0 + col], pack4(v));
    });
}

// ---------------------------------------------------------------------------
// fc2: bf16 in, +bias + fp32 residual (normalized O). Writes bf16 Xb always;
// fp32 X only on the final layer. Row-panel XCD swizzle.
// ---------------------------------------------------------------------------
template <bool WRITE_X>
__global__ __launch_bounds__(256) void fc2_gemm(
    const u16* __restrict__ A, const u16* __restrict__ Bt,
    const float* __restrict__ bias, float* __restrict__ X,
    u16* __restrict__ Xb)
{
    __shared__ __align__(16) u16 SMEM[SMEM_U16];
    u16* As = SMEM; u16* Bs = SMEM + 8192;
    f32x4 acc[4][4];
    int rt, ct; xcd_rc(rt, ct);
    const int row0 = rt * 128, col0 = ct * 128;
    mm_core(A, 2 * CH, Bt, 2 * CH, row0, col0, 2 * CH, As, Bs, acc);
    epi_emit(acc, (float*)SMEM, [&](int row, int col, f32x4 v) {
        const size_t idx = (size_t)(row0 + row) * CH + col0 + col;
        const float4 bb = *(const float4*)&bias[col0 + col];
        const f32x4 xv = *(const f32x4*)&X[idx];
        v[0] += bb.x + xv[0]; v[1] += bb.y + xv[1];
        v[2] += bb.z + xv[2]; v[3] += bb.w + xv[3];
        if (WRITE_X) st16f(&X[idx], v);
        st16(&Xb[idx], pack4(v));
    });
}

// ---------------------------------------------------------------------------
// LayerNorm: fp32 in (normalized attention out), bf16 out (feeds fc1).
// ---------------------------------------------------------------------------
__device__ __forceinline__ float block_sum(float v, volatile float* red, int tid)
{
#pragma unroll
    for (int off = 1; off < 64; off <<= 1) v += __shfl_xor(v, off, 64);
    __syncthreads();
    if ((tid & 63) == 0) red[tid >> 6] = v;
    __syncthreads();
    return red[0] + red[1] + red[2] + red[3];
}

__global__ __launch_bounds__(256) void ln_kernel(
    const float* __restrict__ x, const float* __restrict__ g,
    const float* __restrict__ bta, u16* __restrict__ y)
{
    __shared__ float red[4];
    const int tid = threadIdx.x;
    const size_t base = (size_t)blockIdx.x * CH;
    float x0 = x[base + tid];
    float x1 = x[base + 256 + tid];
    float mu = block_sum(x0 + x1, red, tid) * (1.f / CH);
    float d0 = x0 - mu, d1 = x1 - mu;
    float var = block_sum(d0 * d0 + d1 * d1, red, tid) * (1.f / CH);
    float w = 1.f / sqrtf(var + 1e-5f);
    y[base + tid]       = f2bf(d0 * w * g[tid]       + bta[tid]);
    y[base + 256 + tid] = f2bf(d1 * w * g[256 + tid] + bta[256 + tid]);
}

// ---------------------------------------------------------------------------
// fp32 -> bf16 elementwise (4/thread).
// ---------------------------------------------------------------------------
__global__ __launch_bounds__(256) void f2bf_kernel(
    const float* __restrict__ in, u16* __restrict__ out)
{
    const int i = blockIdx.x * 256 + threadIdx.x;
    float4 v = ((const float4*)in)[i];
    ushort4 o;
    o.x = f2bf(v.x); o.y = f2bf(v.y); o.z = f2bf(v.z); o.w = f2bf(v.w);
    ((ushort4*)out)[i] = o;
}

// ---------------------------------------------------------------------------
// Weight transpose-convert: in fp32 [L][K][N] -> out bf16 [L][N][K].
// ---------------------------------------------------------------------------
__global__ __launch_bounds__(256) void wtrans_kernel(
    const float* __restrict__ in, u16* __restrict__ out, int K, int N)
{
    __shared__ float tile[32][33];
    const int l = blockIdx.z;
    in  += (size_t)l * K * N;
    out += (size_t)l * K * N;
    const int n0 = blockIdx.x * 32, k0 = blockIdx.y * 32;
    const int r = threadIdx.x >> 3, c4 = (threadIdx.x & 7) * 4;
    float4 v = *(const float4*)&in[(size_t)(k0 + r) * N + n0 + c4];
    tile[r][c4 + 0] = v.x; tile[r][c4 + 1] = v.y;
    tile[r][c4 + 2] = v.z; tile[r][c4 + 3] = v.w;
    __syncthreads();
    ushort4 o;
    o.x = f2bf(tile[c4 + 0][r]); o.y = f2bf(tile[c4 + 1][r]);
    o.z = f2bf(tile[c4 + 2][r]); o.w = f2bf(tile[c4 + 3][r]);
    *(ushort4*)&out[(size_t)(n0 + r) * K + k0 + c4] = o;
}

// ---------------------------------------------------------------------------
extern "C" void kernel_launch(void* const* d_in, const int* in_sizes, int n_in,
                              void* d_out, int out_size, void* d_ws, size_t ws_size,
                              hipStream_t stream)
{
    const float* x_in  = (const float*)d_in[0];
    const float* qkv_w = (const float*)d_in[1];
    const float* qkv_b = (const float*)d_in[2];
    const float* ln_g  = (const float*)d_in[3];
    const float* ln_b  = (const float*)d_in[4];
    const float* fc1_w = (const float*)d_in[5];
    const float* fc1_b = (const float*)d_in[6];
    const float* fc2_w = (const float*)d_in[7];
    const float* fc2_b = (const float*)d_in[8];

    float* xbuf = (float*)d_out;   // fp32 working x (B,N,C) — also final out

    // Workspace carve (bytes). Total ≈ 152.7 MB.
    char* p = (char*)d_ws;
    u16* qkv_wt = (u16*)p; p += (size_t)NLAYERS * 1536 * 512 * 2;
    u16* fc1_wt = (u16*)p; p += (size_t)NLAYERS * 1024 * 512 * 2;
    u16* fc2_wt = (u16*)p; p += (size_t)NLAYERS * 512 * 1024 * 2;
    u16* xb = (u16*)p; p += (size_t)ROWS_TOTAL * CH * 2;
    u16* Qb = (u16*)p; p += (size_t)ROWS_TOTAL * CH * 2;
    u16* Kb = (u16*)p; p += (size_t)ROWS_TOTAL * CH * 2;
    u16* Vt = (u16*)p; p += (size_t)ROWS_TOTAL * CH * 2;
    float* rowsum = (float*)p; p += (size_t)ROWS_TOTAL * 4;
    u16* Sb = (u16*)p;                       // attention phase
    u16* yb = Sb;                            // alias: LN out (MLP phase)
    u16* hb = Sb + (size_t)ROWS_TOTAL * CH;  // alias: GELU out (MLP phase)

    const dim3 blk(256);

    f2bf_kernel<<<dim3(ROWS_TOTAL * CH / 1024), blk, 0, stream>>>(x_in, xb);
    wtrans_kernel<<<dim3(1536 / 32, 512 / 32, NLAYERS), blk, 0, stream>>>(
        qkv_w, qkv_wt, 512, 1536);
    wtrans_kernel<<<dim3(1024 / 32, 512 / 32, NLAYERS), blk, 0, stream>>>(
        fc1_w, fc1_wt, 512, 1024);
    wtrans_kernel<<<dim3(512 / 32, 1024 / 32, NLAYERS), blk, 0, stream>>>(
        fc2_w, fc2_wt, 1024, 512);

    for (int l = 0; l < NLAYERS; ++l) {
        qkv_gemm<<<dim3(128 * 12), blk, 0, stream>>>(
            xb, qkv_wt + (size_t)l * 1536 * 512, qkv_b + (size_t)l * 1536,
            Qb, Kb, Vt);
        hipMemsetAsync(rowsum, 0, (size_t)ROWS_TOTAL * 4, stream);
        qk_gemm<<<dim3(2048), blk, 0, stream>>>(Qb, Kb, Sb, rowsum);
        pv_gemm<<<dim3(512), blk, 0, stream>>>(Sb, Vt, rowsum, xbuf);
        ln_kernel<<<dim3(ROWS_TOTAL), blk, 0, stream>>>(
            xbuf, ln_g + (size_t)l * CH, ln_b + (size_t)l * CH, yb);
        fc1_gemm<<<dim3(128 * 8), blk, 0, stream>>>(
            yb, fc1_wt + (size_t)l * 1024 * 512, fc1_b + (size_t)l * 1024, hb);
        if (l < NLAYERS - 1)
            fc2_gemm<false><<<dim3(128 * 4), blk, 0, stream>>>(
                hb, fc2_wt + (size_t)l * 512 * 1024, fc2_b + (size_t)l * 512,
                xbuf, xb);
        else
            fc2_gemm<true><<<dim3(128 * 4), blk, 0, stream>>>(
                hb, fc2_wt + (size_t)l * 512 * 1024, fc2_b + (size_t)l * 512,
                xbuf, xb);
    }
}